// Round 10
// baseline (819.724 us; speedup 1.0000x reference)
//
#include <hip/hip_runtime.h>

#define G60 60
#define KN 13

typedef unsigned int u32;
typedef unsigned short u16;
typedef short short8 __attribute__((ext_vector_type(8)));
typedef float f32x4 __attribute__((ext_vector_type(4)));
typedef float f32x16 __attribute__((ext_vector_type(16)));
typedef u32 u32x4 __attribute__((ext_vector_type(4)));

// compile-time for loop: every index is a literal -> registers guaranteed
template <int I> struct Ic { static constexpr int v = I; };
template <int I, int N, typename F>
__device__ __forceinline__ void sfor(F&& f) {
    if constexpr (I < N) { f(Ic<I>{}); sfor<I + 1, N>(f); }
}

// ---- split-bf16 helpers ----------------------------------------------------
__device__ __forceinline__ u32 f32_to_packed(float v) {
    u32 u = __float_as_uint(v);
    u32 hi = (u + 0x7FFFu + ((u >> 16) & 1u)) >> 16;      // RNE bf16 of v
    float vhi = __uint_as_float(hi << 16);
    float lof = v - vhi;
    u32 ul = __float_as_uint(lof);
    u32 lo = (ul + 0x7FFFu + ((ul >> 16) & 1u)) >> 16;    // RNE bf16 of residual
    return (hi << 16) | lo;
}
__device__ __forceinline__ float packed_f32(u32 w) {
    return __uint_as_float(w & 0xFFFF0000u) + __uint_as_float(w << 16);
}

// ---- fused weight pack: all 4 layers in one dispatch -----------------------
// W[o][c][k] -> 32x32x16 MFMA B-frag order, hi/lo planes.
// chunk t = (ct*13 + kk)*SUBS + sub ; element id = ((t*NTt + nt)*64 + lane)*8 + j
// o = nt*32 + (lane&31); c = ct*CT + sub*16 + (lane>>5)*8 + j
__device__ __forceinline__ void pack_one(const float* __restrict__ W,
                                         u16* __restrict__ Whi, u16* __restrict__ Wlo,
                                         int C, int O, int CT, int id) {
    int j = id & 7;
    int lane = (id >> 3) & 63;
    int fid = id >> 9;
    int NTt = O >> 5;
    int nt = fid % NTt;
    int t = fid / NTt;
    int SUBS = CT >> 4;
    int sub = t % SUBS;
    int kk = (t / SUBS) % KN;
    int ct = t / (KN * SUBS);
    int q = lane >> 5, n = lane & 31;
    int o = nt * 32 + n;
    int c = ct * CT + sub * 16 + q * 8 + j;
    u32 pw = f32_to_packed(W[((size_t)o * C + c) * KN + kk]);
    Whi[id] = (u16)(pw >> 16);
    Wlo[id] = (u16)(pw & 0xFFFFu);
}

__global__ void __launch_bounds__(256) pack_all_kern(
    const float* W_in, u16* Whi_in, u16* Wlo_in,
    const float* W1, u16* Whi_1, u16* Wlo_1,
    const float* W2, u16* Whi_2, u16* Wlo_2,
    const float* Wo, u16* Whi_o, u16* Wlo_o) {
    const int T0 = KN * 32 * 256;            // conv_in (CT=32)
    const int T1 = T0 + KN * 256 * 512;      // conv1
    const int T2 = T1 + KN * 512 * 256;      // conv2
    const int T3 = T2 + KN * 256 * 32;       // conv_out
    int id = blockIdx.x * 256 + threadIdx.x;
    if (id < T0) pack_one(W_in, Whi_in, Wlo_in, 32, 256, 32, id);
    else if (id < T1) pack_one(W1, Whi_1, Wlo_1, 256, 512, 64, id - T0);
    else if (id < T2) pack_one(W2, Whi_2, Wlo_2, 512, 256, 64, id - T1);
    else if (id < T3) pack_one(Wo, Whi_o, Wlo_o, 256, 32, 64, id - T2);
}

// ---- 32x32x16 MFMA comb-conv: bsplit x nsplit waves ------------------------
// Block stages NBS batches into LDS. Waves = NBS bsplit x NNS nsplit; each
// wave computes 1 batch x M=64 (2 m-tiles) x NTB N-tiles. The NBS waves with
// equal ns read identical W fragments (L1-shared), so block-level W L2
// traffic is amortized over NBS batches while per-wave LDS reads stay at
// 341 B/MFMA (NTB=2). B double-buffered in regs via static sfor.
// SRC: 0 packed u32, 1 fp32 (pack inline), 2 combine-2-fp32-partials+BN+ReLU
// +packed-residual. OUTF32: fp32 partial plane indexed by blockIdx.z.
template <int CT, int NBS, int NNS, int NTB, int SRC, bool BNR, bool OUTF32>
__global__ void __launch_bounds__(NBS * NNS * 64, 2) mconv7(
    const u32* __restrict__ Xp, const float* __restrict__ Xf,
    const float* __restrict__ pIn,
    const float* __restrict__ bnb, const float* __restrict__ bng,
    const float* __restrict__ bnB,
    const u32* __restrict__ resid,
    const u16* __restrict__ Whi, const u16* __restrict__ Wlo,
    const float* __restrict__ bias, const float* __restrict__ gamma,
    const float* __restrict__ beta,
    const int* __restrict__ nei,
    u32* __restrict__ outp, float* __restrict__ outf,
    int C, int O, int tpz) {
    constexpr int SUBS = CT >> 4;
    constexpr int S = KN * SUBS;           // K-steps per ct tile
    constexpr int NG = S / 2;              // groups of 2 steps
    constexpr int STRIDE = CT + 8;         // u16; rows 16B-aligned
    constexpr int PLSZ = G60 * STRIDE;     // u16 per plane
    constexpr int THREADS = NBS * NNS * 64;
    __shared__ u16 Xs[NBS * 2 * PLSZ];
    const int tid = threadIdx.x;
    const int lane = tid & 63;
    const int wv = tid >> 6;
    const int bs = wv / NNS;               // batch-split index
    const int ns = wv - bs * NNS;          // n-split index
    const int q = lane >> 5;
    const int m = lane & 31;
    const int bp = blockIdx.x;             // batch-group
    const int b = bp * NBS + bs;
    const int NTt = O >> 5;
    const int nt0 = ((int)blockIdx.y * NNS + ns) * NTB;
    const int ct0 = (int)blockIdx.z * tpz;
    const int pb0 = bs * 2 * PLSZ;         // this wave's batch planes in LDS
    const size_t PLi = (size_t)256 * C * G60;
    float* outfz = OUTF32 ? (outf + (size_t)blockIdx.z * ((size_t)256 * O * G60)) : nullptr;

    int rowoff[2][KN];
#pragma unroll
    for (int mt = 0; mt < 2; ++mt) {
        int g = mt * 32 + m;
        int gl = (g < G60) ? g : 0;
#pragma unroll
        for (int kk = 0; kk < KN; ++kk) rowoff[mt][kk] = nei[gl * KN + kk] * STRIDE;
    }

    f32x16 acc[2][NTB];
#pragma unroll
    for (int mt = 0; mt < 2; ++mt)
#pragma unroll
        for (int nt = 0; nt < NTB; ++nt) acc[mt][nt] = (f32x16)(0.f);

    short8 Bh[2][2][NTB], Bl[2][2][NTB];   // [buf][step-in-group][nt]

    for (int ct = ct0; ct < ct0 + tpz; ++ct) {
        const size_t fbase = ((size_t)(ct * S) * NTt + nt0) * 512 + (size_t)lane * 8;

        __syncthreads();
        constexpr int PAIRS = (CT / 2) * G60;
        for (int i = tid; i < NBS * PAIRS; i += THREADS) {
            int bb = i / PAIRS;
            int r = i - bb * PAIRS;
            int ccp = (r * 17477) >> 20;   // r/60, exact for r<3840
            int g = r - ccp * G60;
            int cc = ccp * 2;
            size_t cg0 = ((size_t)(bp * NBS + bb) * C + (size_t)ct * CT + cc) * G60 + g;
            u32 w0, w1;
            if (SRC == 0) {
                w0 = Xp[cg0]; w1 = Xp[cg0 + G60];
            } else if (SRC == 1) {
                w0 = f32_to_packed(Xf[cg0]); w1 = f32_to_packed(Xf[cg0 + G60]);
            } else {
                int c0 = ct * CT + cc;
                float v0 = pIn[cg0] + pIn[PLi + cg0];
                float v1 = pIn[cg0 + G60] + pIn[PLi + cg0 + G60];
                v0 = fmaxf((v0 + bnb[c0]) * bng[c0] + bnB[c0], 0.f) + packed_f32(resid[cg0]);
                v1 = fmaxf((v1 + bnb[c0 + 1]) * bng[c0 + 1] + bnB[c0 + 1], 0.f) + packed_f32(resid[cg0 + G60]);
                w0 = f32_to_packed(v0); w1 = f32_to_packed(v1);
            }
            int rb = bb * 2 * PLSZ + g * STRIDE + cc;
            *(u32*)(Xs + rb) = (w0 >> 16) | (w1 & 0xFFFF0000u);          // hi plane
            *(u32*)(Xs + rb + PLSZ) = (w0 & 0xFFFFu) | (w1 << 16);       // lo plane
        }

        // group-0 B prefetch issued before the barrier (independent of LDS)
        sfor<0, 2>([&](auto uc) {
            constexpr int u = decltype(uc)::v;
            sfor<0, NTB>([&](auto nc) {
                constexpr int nt = decltype(nc)::v;
                const size_t fb = fbase + ((size_t)u * NTt + nt) * 512;
                Bh[0][u][nt] = *reinterpret_cast<const short8*>(Whi + fb);
                Bl[0][u][nt] = *reinterpret_cast<const short8*>(Wlo + fb);
            });
        });
        __syncthreads();

        sfor<0, NG>([&](auto gc) {
            constexpr int g = decltype(gc)::v;
            constexpr int pb = g & 1;
            if constexpr (g + 1 < NG) {
                constexpr int pn = (g + 1) & 1;
                sfor<0, 2>([&](auto uc) {
                    constexpr int u = decltype(uc)::v;
                    constexpr int s = 2 * (g + 1) + u;
                    sfor<0, NTB>([&](auto nc) {
                        constexpr int nt = decltype(nc)::v;
                        const size_t fb = fbase + ((size_t)s * NTt + nt) * 512;
                        Bh[pn][u][nt] = *reinterpret_cast<const short8*>(Whi + fb);
                        Bl[pn][u][nt] = *reinterpret_cast<const short8*>(Wlo + fb);
                    });
                });
            }
            // A fragments for group g: 2 steps x 2 mt x 2 planes (this batch)
            short8 Ah[2][2], Al[2][2];
            sfor<0, 2>([&](auto uc) {
                constexpr int u = decltype(uc)::v;
                constexpr int s = 2 * g + u;
                constexpr int kk = s / SUBS;
                constexpr int sub = s - kk * SUBS;
                sfor<0, 2>([&](auto mc) {
                    constexpr int mt = decltype(mc)::v;
                    const int off = pb0 + rowoff[mt][kk] + sub * 16 + q * 8;
                    Ah[u][mt] = *reinterpret_cast<const short8*>(Xs + off);
                    Al[u][mt] = *reinterpret_cast<const short8*>(Xs + off + PLSZ);
                });
            });
            // MFMAs: per step 3 passes x 2mt x NTB
            sfor<0, 2>([&](auto uc) {
                constexpr int u = decltype(uc)::v;
                sfor<0, NTB>([&](auto nc) {
                    constexpr int nt = decltype(nc)::v;
                    sfor<0, 2>([&](auto mc) {
                        constexpr int mt = decltype(mc)::v;
                        acc[mt][nt] = __builtin_amdgcn_mfma_f32_32x32x16_bf16(
                            Ah[u][mt], Bh[pb][u][nt], acc[mt][nt], 0, 0, 0);
                    });
                });
                sfor<0, NTB>([&](auto nc) {
                    constexpr int nt = decltype(nc)::v;
                    sfor<0, 2>([&](auto mc) {
                        constexpr int mt = decltype(mc)::v;
                        acc[mt][nt] = __builtin_amdgcn_mfma_f32_32x32x16_bf16(
                            Ah[u][mt], Bl[pb][u][nt], acc[mt][nt], 0, 0, 0);
                    });
                });
                sfor<0, NTB>([&](auto nc) {
                    constexpr int nt = decltype(nc)::v;
                    sfor<0, 2>([&](auto mc) {
                        constexpr int mt = decltype(mc)::v;
                        acc[mt][nt] = __builtin_amdgcn_mfma_f32_32x32x16_bf16(
                            Al[u][mt], Bh[pb][u][nt], acc[mt][nt], 0, 0, 0);
                    });
                });
            });
        });
    }

    // epilogue. C/D: col(o)=lane&31, row-in-tile = (r&3)+8*(r>>2)+4*q [m74/m101]
#pragma unroll
    for (int nt = 0; nt < NTB; ++nt) {
        const int o = (nt0 + nt) * 32 + m;
        float bi = 0.f, ga = 1.f, be = 0.f;
        if (!OUTF32) { bi = bias[o]; if (BNR) { ga = gamma[o]; be = beta[o]; } }
#pragma unroll
        for (int mt = 0; mt < 2; ++mt) {
#pragma unroll
            for (int grp = 0; grp < 4; ++grp) {
                const int g0 = mt * 32 + grp * 8 + q * 4;
                if (g0 < G60) {
                    size_t oi = ((size_t)b * O + o) * G60 + g0;
                    if (OUTF32) {
                        f32x4 v;
#pragma unroll
                        for (int rr = 0; rr < 4; ++rr) v[rr] = acc[mt][nt][grp * 4 + rr];
                        *reinterpret_cast<f32x4*>(outfz + oi) = v;
                    } else {
                        u32x4 pv;
#pragma unroll
                        for (int rr = 0; rr < 4; ++rr) {
                            float v = acc[mt][nt][grp * 4 + rr] + bi;
                            if (BNR) v = fmaxf(v * ga + be, 0.f);
                            pv[rr] = f32_to_packed(v);
                        }
                        *reinterpret_cast<u32x4*>(outp + oi) = pv;
                    }
                }
            }
        }
    }
}

// ---- finalize: sum 4 conv_out partials, BN+ReLU, +feats, norms; also emits
// the feats passthrough output. ----------------------------------------------
__global__ void __launch_bounds__(64) finalize_kern(
    const float* __restrict__ pout,          // [4][B][32][60] fp32 partials
    const float* __restrict__ feats,         // [B][32][60]
    const float* __restrict__ bo, const float* __restrict__ go,
    const float* __restrict__ beo,
    float* __restrict__ out_feats,           // [B][32][60] passthrough
    float* __restrict__ out_eqv,             // [B][32][60]
    float* __restrict__ out_inv) {           // [B][32]
    const int b = blockIdx.x;
    const size_t PB = (size_t)256 * 32 * G60;
    __shared__ float E[32 * G60];
    __shared__ float gnorm[G60];
    __shared__ float inv_pre[32];
    __shared__ float inv_nrm;
    const int tid = threadIdx.x;

    for (int i = tid; i < 32 * G60; i += 64) {
        int f = i / G60;
        size_t idx = (size_t)b * 1920 + i;
        float ft = feats[idx];
        out_feats[idx] = ft;
        float s = pout[idx] + pout[PB + idx] + pout[2 * PB + idx] + pout[3 * PB + idx];
        float v = fmaxf((s + bo[f]) * go[f] + beo[f], 0.f);
        E[i] = v + ft;
    }
    __syncthreads();
    if (tid < G60) {
        float s = 0.f;
        for (int f = 0; f < 32; ++f) { float v = E[f * G60 + tid]; s += v * v; }
        gnorm[tid] = fmaxf(sqrtf(s), 1e-4f);
    }
    if (tid < 32) {
        float s = 0.f;
        for (int g = 0; g < G60; ++g) s += E[tid * G60 + g];
        inv_pre[tid] = s / 60.f;
    }
    __syncthreads();
    if (tid == 0) {
        float s = 0.f;
        for (int f = 0; f < 32; ++f) s += inv_pre[f] * inv_pre[f];
        inv_nrm = fmaxf(sqrtf(s), 1e-4f);
    }
    __syncthreads();
    for (int i = tid; i < 1920; i += 64) {
        int g = i % G60;
        out_eqv[(size_t)b * 1920 + i] = E[i] / gnorm[g];
    }
    if (tid < 32) out_inv[b * 32 + tid] = inv_pre[tid] / inv_nrm;
}

// ---- des2dr: 256 thr/block, 4-way channel split per rotation a -------------
__global__ void __launch_bounds__(256) des2dr_kern(
    const float* __restrict__ e0f, const float* __restrict__ e1f,
    const int* __restrict__ permu, int* __restrict__ pre_int,
    float* __restrict__ out_pre) {
    const int b = blockIdx.x;
    __shared__ float X0[32 * G60];
    __shared__ float X1[32 * G60];
    __shared__ float pc[256];
    __shared__ float cor[64];
    const int tid = threadIdx.x;
    for (int i = tid; i < 1920; i += 256) {
        X0[i] = e0f[(size_t)b * 1920 + i];
        X1[i] = e1f[(size_t)b * 1920 + i];
    }
    __syncthreads();
    const int a = tid >> 2, fc = tid & 3;
    float s = 0.f;
    if (a < G60) {
        for (int g = 0; g < G60; ++g) {
            int p = permu[a * G60 + g];
#pragma unroll
            for (int f = fc * 8; f < fc * 8 + 8; ++f) s += X0[f * G60 + p] * X1[f * G60 + g];
        }
    }
    pc[tid] = s;
    __syncthreads();
    if (tid < 64) cor[tid] = pc[4 * tid] + pc[4 * tid + 1] + pc[4 * tid + 2] + pc[4 * tid + 3];
    __syncthreads();
    if (tid == 0) {
        float best = cor[0];
        int bi = 0;
        for (int a2 = 1; a2 < G60; ++a2)
            if (cor[a2] > best) { best = cor[a2]; bi = a2; }  // first-max = jnp.argmax
        pre_int[b] = bi;
        out_pre[b] = (float)bi;
    }
}

__global__ void __launch_bounds__(256) ability_kern(
    const int* __restrict__ pre_int, const int* __restrict__ true_idx,
    float* __restrict__ out_ability, float* __restrict__ out_true) {
    __shared__ int cnt[256];
    const int t = threadIdx.x;
    cnt[t] = (pre_int[t] == true_idx[t]) ? 1 : 0;
    out_true[t] = (float)true_idx[t];
    __syncthreads();
    for (int s = 128; s > 0; s >>= 1) {
        if (t < s) cnt[t] += cnt[t + s];
        __syncthreads();
    }
    if (t == 0) out_ability[0] = (float)cnt[0] / 256.0f;
}

extern "C" void kernel_launch(void* const* d_in, const int* in_sizes, int n_in,
                              void* d_out, int out_size, void* d_ws, size_t ws_size,
                              hipStream_t stream) {
    const float* feats0 = (const float*)d_in[0];
    const float* feats1 = (const float*)d_in[1];
    const int* true_idx = (const int*)d_in[2];
    const int* nei = (const int*)d_in[3];
    const int* permu = (const int*)d_in[4];
    const float* W_in = (const float*)d_in[5];
    const float* b_in = (const float*)d_in[6];
    const float* W1 = (const float*)d_in[7];
    const float* b1 = (const float*)d_in[8];
    const float* g1 = (const float*)d_in[9];
    const float* be1 = (const float*)d_in[10];
    const float* W2 = (const float*)d_in[11];
    const float* b2 = (const float*)d_in[12];
    const float* g2 = (const float*)d_in[13];
    const float* be2 = (const float*)d_in[14];
    const float* Wo = (const float*)d_in[15];
    const float* bo = (const float*)d_in[16];
    const float* go = (const float*)d_in[17];
    const float* beo = (const float*)d_in[18];

    float* out = (float*)d_out;
    const size_t SZF = (size_t)256 * 32 * G60;  // 491520
    float* out_f0 = out;
    float* out_f1 = out + SZF;
    float* out_e0 = out + 2 * SZF;
    float* out_e1 = out + 3 * SZF;
    float* out_i0 = out + 4 * SZF;
    float* out_i1 = out_i0 + 256 * 32;
    float* out_ab = out_i1 + 256 * 32;
    float* out_tr = out_ab + 1;
    float* out_pr = out_tr + 256;

    // ---- workspace layout (~101 MB, unchanged footprint) ----
    char* p = (char*)d_ws;
    auto alloc = [&](size_t bytes) { char* r = p; p += (bytes + 255) & ~(size_t)255; return r; };
    const size_t NW_IN = (size_t)KN * 32 * 256;
    const size_t NW_1 = (size_t)KN * 256 * 512;
    const size_t NW_2 = (size_t)KN * 512 * 256;
    const size_t NW_O = (size_t)KN * 256 * 32;
    u16* Whi_in = (u16*)alloc(NW_IN * 2); u16* Wlo_in = (u16*)alloc(NW_IN * 2);
    u16* Whi_1 = (u16*)alloc(NW_1 * 2);   u16* Wlo_1 = (u16*)alloc(NW_1 * 2);
    u16* Whi_2 = (u16*)alloc(NW_2 * 2);   u16* Wlo_2 = (u16*)alloc(NW_2 * 2);
    u16* Whi_o = (u16*)alloc(NW_O * 2);   u16* Wlo_o = (u16*)alloc(NW_O * 2);
    u32* dbuf = (u32*)alloc((size_t)256 * 256 * G60 * 4);        // conv_in out, packed
    u32* fcbuf = (u32*)alloc((size_t)256 * 512 * G60 * 4);       // conv1 out, packed
    float* p2 = (float*)alloc((size_t)2 * 256 * 256 * G60 * 4);  // conv2 K-split partials
    float* pout = (float*)alloc((size_t)4 * SZF * 4);            // conv_out K-split partials
    int* pre_int = (int*)alloc(256 * 4);

    // ---- fused weight pack (1 dispatch) ----
    {
        int total = KN * (32 * 256 + 256 * 512 + 512 * 256 + 256 * 32);
        pack_all_kern<<<dim3((total + 255) / 256), dim3(256), 0, stream>>>(
            W_in, Whi_in, Wlo_in, W1, Whi_1, Wlo_1, W2, Whi_2, Wlo_2, Wo, Whi_o, Wlo_o);
    }

    for (int net = 0; net < 2; ++net) {
        const float* feats = net ? feats1 : feats0;
        float* of = net ? out_f1 : out_f0;
        float* oe = net ? out_e1 : out_e0;
        float* oi = net ? out_i1 : out_i0;

        // conv_in: 32 -> 256, fp32 src packed inline. 2bs x 2ns x NTB2.
        // grid (128, 2): 256 blocks. NTt=8 = 2y * 2ns * 2ntb.
        mconv7<32, 2, 2, 2, 1, false, false><<<dim3(128, 2, 1), dim3(256), 0, stream>>>(
            nullptr, feats, nullptr, nullptr, nullptr, nullptr, nullptr,
            Whi_in, Wlo_in, b_in, nullptr, nullptr, nei, dbuf, nullptr, 32, 256, 1);
        // conv1: 256 -> 512, BN+ReLU packed. grid (128, 4): NTt=16 = 4y*2ns*2ntb.
        mconv7<64, 2, 2, 2, 0, true, false><<<dim3(128, 4, 1), dim3(256), 0, stream>>>(
            dbuf, nullptr, nullptr, nullptr, nullptr, nullptr, nullptr,
            Whi_1, Wlo_1, b1, g1, be1, nei, fcbuf, nullptr, 256, 512, 4);
        // conv2: 512 -> 256, fp32 partials, z=2 K-split. grid (128, 2, 2).
        mconv7<64, 2, 2, 2, 0, false, true><<<dim3(128, 2, 2), dim3(256), 0, stream>>>(
            fcbuf, nullptr, nullptr, nullptr, nullptr, nullptr, nullptr,
            Whi_2, Wlo_2, nullptr, nullptr, nullptr, nei, nullptr, p2, 512, 256, 4);
        // conv_out: 256 -> 32. Staging fuses p2 combine + b2/g2/be2 BN+ReLU
        // + residual(dbuf). fp32 partials z=4. 2bs x 1ns x NTB1. grid (128,1,4).
        mconv7<64, 2, 1, 1, 2, false, true><<<dim3(128, 1, 4), dim3(128), 0, stream>>>(
            nullptr, nullptr, p2, b2, g2, be2, dbuf,
            Whi_o, Wlo_o, nullptr, nullptr, nullptr, nei, nullptr, pout, 256, 32, 1);
        // finalize: sum partials + bo/go/beo BN+ReLU + feats + norms + passthrough
        finalize_kern<<<dim3(256), dim3(64), 0, stream>>>(pout, feats, bo, go, beo, of, oe, oi);
    }

    des2dr_kern<<<dim3(256), dim3(256), 0, stream>>>(out_e0, out_e1, permu, pre_int, out_pr);
    ability_kern<<<dim3(1), dim3(256), 0, stream>>>(pre_int, true_idx, out_ab, out_tr);

    (void)in_sizes; (void)n_in; (void)out_size; (void)ws_size;
}